// Round 2
// baseline (13059.943 us; speedup 1.0000x reference)
//
#include <hip/hip_runtime.h>
#include <cstdint>
#include <cstddef>

#define T_ 256
#define B_ 128
#define E_ 512
#define H_ 1024
#define BH (B_*H_)

typedef _Float16 v8h __attribute__((ext_vector_type(8)));
typedef float    v4f __attribute__((ext_vector_type(4)));

__device__ __forceinline__ float sigmoidf_(float x){ return 1.0f/(1.0f+__expf(-x)); }
__device__ __forceinline__ float tanhf_(float x){ return 1.0f - 2.0f/(__expf(2.0f*x)+1.0f); }

// Device-scope spin barrier. Monotone counter in ws (zeroed each launch).
// Safe: 256 WGs, 64KB LDS -> worst-case 2 WG/CU packing still leaves all
// 256 WGs resident on >=128 CUs.
__device__ __forceinline__ void grid_barrier(unsigned int* cnt, unsigned int target) {
    __syncthreads();
    if (threadIdx.x == 0) {
        __hip_atomic_fetch_add(cnt, 1u, __ATOMIC_RELEASE, __HIP_MEMORY_SCOPE_AGENT);
        while (__hip_atomic_load(cnt, __ATOMIC_ACQUIRE, __HIP_MEMORY_SCOPE_AGENT) < target) {
            __builtin_amdgcn_s_sleep(4);
        }
    }
    __syncthreads();
}

// One K-segment of the per-step GEMM. Wave-private: no syncthreads inside.
// Out tile: rows [rtile, rtile+64) x h-cols [ctile, ctile+16) (48 gate cols).
// A/B fragments loaded directly global->VGPR (16B/lane = full-line coalesced).
// 16x16x32 f16 MFMA; layouts as verified in round 1:
//   A: row = lane&15, k = (lane>>4)*8 + j ; B: col = lane&15, same k
//   C: col = lane&15, row = (lane>>4)*4 + reg
__device__ __forceinline__ void gemm_seg(
    v4f (&accR)[4], v4f (&accZ)[4], v4f (&accN)[4],
    const _Float16* __restrict__ aseg, int apitch,
    const _Float16* __restrict__ bseg, int bpitch,
    int rtile, int ctile, int ks0, int ksN, int lane)
{
    if (ksN <= ks0) return;
    const int row = lane & 15, hi = lane >> 4;
    const _Float16* ap0 = aseg + (size_t)(rtile +  0 + row) * apitch + ks0*32 + hi*8;
    const _Float16* ap1 = aseg + (size_t)(rtile + 16 + row) * apitch + ks0*32 + hi*8;
    const _Float16* ap2 = aseg + (size_t)(rtile + 32 + row) * apitch + ks0*32 + hi*8;
    const _Float16* ap3 = aseg + (size_t)(rtile + 48 + row) * apitch + ks0*32 + hi*8;
    const _Float16* bp0 = bseg + (size_t)(0*H_ + ctile + row) * bpitch + ks0*32 + hi*8;
    const _Float16* bp1 = bseg + (size_t)(1*H_ + ctile + row) * bpitch + ks0*32 + hi*8;
    const _Float16* bp2 = bseg + (size_t)(2*H_ + ctile + row) * bpitch + ks0*32 + hi*8;
    for (int ks = ks0; ks < ksN; ++ks) {
        v8h a0 = *(const v8h*)ap0;
        v8h a1 = *(const v8h*)ap1;
        v8h a2 = *(const v8h*)ap2;
        v8h a3 = *(const v8h*)ap3;
        v8h b0 = *(const v8h*)bp0;
        v8h b1 = *(const v8h*)bp1;
        v8h b2 = *(const v8h*)bp2;
        accR[0] = __builtin_amdgcn_mfma_f32_16x16x32_f16(a0, b0, accR[0], 0,0,0);
        accR[1] = __builtin_amdgcn_mfma_f32_16x16x32_f16(a1, b0, accR[1], 0,0,0);
        accR[2] = __builtin_amdgcn_mfma_f32_16x16x32_f16(a2, b0, accR[2], 0,0,0);
        accR[3] = __builtin_amdgcn_mfma_f32_16x16x32_f16(a3, b0, accR[3], 0,0,0);
        accZ[0] = __builtin_amdgcn_mfma_f32_16x16x32_f16(a0, b1, accZ[0], 0,0,0);
        accZ[1] = __builtin_amdgcn_mfma_f32_16x16x32_f16(a1, b1, accZ[1], 0,0,0);
        accZ[2] = __builtin_amdgcn_mfma_f32_16x16x32_f16(a2, b1, accZ[2], 0,0,0);
        accZ[3] = __builtin_amdgcn_mfma_f32_16x16x32_f16(a3, b1, accZ[3], 0,0,0);
        accN[0] = __builtin_amdgcn_mfma_f32_16x16x32_f16(a0, b2, accN[0], 0,0,0);
        accN[1] = __builtin_amdgcn_mfma_f32_16x16x32_f16(a1, b2, accN[1], 0,0,0);
        accN[2] = __builtin_amdgcn_mfma_f32_16x16x32_f16(a2, b2, accN[2], 0,0,0);
        accN[3] = __builtin_amdgcn_mfma_f32_16x16x32_f16(a3, b2, accN[3], 0,0,0);
        ap0 += 32; ap1 += 32; ap2 += 32; ap3 += 32;
        bp0 += 32; bp1 += 32; bp2 += 32;
    }
}

// Persistent fused 2-layer packed-seq GRU. 256 WGs x 256 thr.
// WGs 0..127: layer0 at t=k; WGs 128..255: layer1 at t=k-1 (pipelined).
// One grid barrier per k. h: fp32 master + fp16 ping-pong shadows.
// WG tile: 64 rows x 16 h-cols. 4 waves K-split; LDS reduce + inline epilogue.
__global__ __launch_bounds__(256) void gru_persist(
    const int* __restrict__ bs, const _Float16* __restrict__ x16,
    const _Float16* __restrict__ Wi0, const _Float16* __restrict__ Wh0,
    const _Float16* __restrict__ Wi1, const _Float16* __restrict__ Wh1,
    const float* __restrict__ bias,
    float* __restrict__ h0f, float* __restrict__ h1f,
    _Float16* __restrict__ h0h, _Float16* __restrict__ h1h,
    _Float16* __restrict__ hn0,
    unsigned int* __restrict__ barrier_cnt)
{
    __shared__ float red[4][4][4][256];   // [wave][gate r,z,ni,nh][m-frag][16x16 fp32]

    const int b = blockIdx.x;
    const int phase = b >> 7;
    const int bl = b & 127;
    // bl = jhi*16 + mt*8 + jlo : weight-slice partners (mt 0/1) 8 apart -> same XCD
    const int mt  = (bl >> 3) & 1;
    const int jt  = ((bl >> 4) << 3) | (bl & 7);   // [0,64)
    const int rtile = mt * 64;
    const int ctile = jt * 16;

    const int tid = threadIdx.x, lane = tid & 63, w = tid >> 6;

    for (int k = 0; k <= T_; ++k) {
        const int t = phase ? (k - 1) : k;
        const bool run = phase ? (k > 0) : (k < T_);
        if (run) {
            const int bs_t = bs[t];
            if (rtile < bs_t) {
                const int pr = t & 1, pw = 1 - pr;
                v4f accR[4], accZ[4], accNi[4], accNh[4];
#pragma unroll
                for (int m = 0; m < 4; ++m) {
                    accR[m] = (v4f){0.f,0.f,0.f,0.f}; accZ[m]  = (v4f){0.f,0.f,0.f,0.f};
                    accNi[m] = (v4f){0.f,0.f,0.f,0.f}; accNh[m] = (v4f){0.f,0.f,0.f,0.f};
                }
                if (phase == 0) {
                    // K = 512 (x) + 1024 (h0): ksteps 0..48, wave w: [12w, 12w+12)
                    const int lo = 12 * w, hi_ = lo + 12;
                    gemm_seg(accR, accZ, accNi, x16 + (size_t)t * B_ * E_, E_, Wi0, E_,
                             rtile, ctile, lo, (hi_ < 16 ? hi_ : 16), lane);
                    gemm_seg(accR, accZ, accNh, h0h + (size_t)pr * BH, H_, Wh0, H_,
                             rtile, ctile, (lo - 16 > 0 ? lo - 16 : 0), hi_ - 16, lane);
                } else {
                    // K = 1024 (hn0) + 1024 (h1): ksteps 0..64, wave w: [16w, 16w+16)
                    const int lo = 16 * w, hi_ = lo + 16;
                    gemm_seg(accR, accZ, accNi, hn0 + (size_t)pr * BH, H_, Wi1, H_,
                             rtile, ctile, lo, (hi_ < 32 ? hi_ : 32), lane);
                    gemm_seg(accR, accZ, accNh, h1h + (size_t)pr * BH, H_, Wh1, H_,
                             rtile, ctile, (lo - 32 > 0 ? lo - 32 : 0), hi_ - 32, lane);
                }
                // cross-wave K-reduction via LDS
#pragma unroll
                for (int m = 0; m < 4; ++m) {
                    *(v4f*)&red[w][0][m][lane * 4] = accR[m];
                    *(v4f*)&red[w][1][m][lane * 4] = accZ[m];
                    *(v4f*)&red[w][2][m][lane * 4] = accNi[m];
                    *(v4f*)&red[w][3][m][lane * 4] = accNh[m];
                }
                __syncthreads();
                v4f r4 = accR[w], z4 = accZ[w], n4i = accNi[w], n4h = accNh[w];
#pragma unroll
                for (int w2 = 0; w2 < 4; ++w2) {
                    if (w2 == w) continue;
                    r4  += *(const v4f*)&red[w2][0][w][lane * 4];
                    z4  += *(const v4f*)&red[w2][1][w][lane * 4];
                    n4i += *(const v4f*)&red[w2][2][w][lane * 4];
                    n4h += *(const v4f*)&red[w2][3][w][lane * 4];
                }
                // epilogue: wave w owns rows [rtile+16w, +16)
                const float* bb = bias + phase * 4 * H_;
                const int col = ctile + (lane & 15);
                const float br_ = bb[col], bz_ = bb[H_ + col];
                const float bi_ = bb[2 * H_ + col], bh_ = bb[3 * H_ + col];
                float* hf = phase ? h1f : h0f;
                _Float16* hh_w = (phase ? h1h : h0h) + (size_t)pw * BH;
                _Float16* hn0w = hn0 + (size_t)pr * BH;
#pragma unroll
                for (int reg = 0; reg < 4; ++reg) {
                    const int row = rtile + 16 * w + (lane >> 4) * 4 + reg;
                    const size_t off = (size_t)row * H_ + col;
                    const float hprev = hf[off];
                    const float rr = sigmoidf_(r4[reg] + br_);
                    const float zz = sigmoidf_(z4[reg] + bz_);
                    const float nn = tanhf_(n4i[reg] + bi_ + rr * (n4h[reg] + bh_));
                    const float hnew = (1.0f - zz) * nn + zz * hprev;
                    const bool act = row < bs_t;
                    if (phase == 0) hn0w[off] = (_Float16)hnew;  // layer1 input (unmasked)
                    hh_w[off] = (_Float16)(act ? hnew : hprev);
                    if (act) hf[off] = hnew;
                }
            }
            // fully-inactive tiles: shadows of rows >= bs_t are never read as
            // GEMM A-operands (a row's A-reads only come from its own row-tile's
            // WGs, which are inactive together); epilogue hprev comes from the
            // fp32 master. No copy-forward needed.
        }
        grid_barrier(barrier_cnt, 256u * (unsigned)(k + 1));
    }
}

// ---------------------------------------------------------------------------
__global__ void cvt_f32_f16(const float* __restrict__ s, _Float16* __restrict__ d, int n) {
    int i = (blockIdx.x * 256 + threadIdx.x) * 8;
    if (i >= n) return;
    float4 v0 = *(const float4*)(s + i);
    float4 v1 = *(const float4*)(s + i + 4);
    v8h o = { (_Float16)v0.x, (_Float16)v0.y, (_Float16)v0.z, (_Float16)v0.w,
              (_Float16)v1.x, (_Float16)v1.y, (_Float16)v1.z, (_Float16)v1.w };
    *(v8h*)(d + i) = o;
}

__global__ void prep_bias(const float* __restrict__ bi0, const float* __restrict__ bh0,
                          const float* __restrict__ bi1, const float* __restrict__ bh1,
                          float* __restrict__ bias) {
    int tid = blockIdx.x * 256 + threadIdx.x;   // 2048 threads
    int l = tid >> 10, j = tid & 1023;
    const float* bi = l ? bi1 : bi0;
    const float* bh = l ? bh1 : bh0;
    float* o = bias + l * 4 * H_;
    o[j]          = bi[j] + bh[j];
    o[H_ + j]     = bi[H_ + j] + bh[H_ + j];
    o[2 * H_ + j] = bi[2 * H_ + j];
    o[3 * H_ + j] = bh[2 * H_ + j];
}

__global__ void gather_out(const float* __restrict__ h0f, const float* __restrict__ h1f,
                           const int* __restrict__ unsorted, float* __restrict__ out) {
    int rowid = blockIdx.x;          // 256 = L*B
    int l = rowid >> 7, b = rowid & 127;
    int src = unsorted[b];
    const float* s = (l ? h1f : h0f) + (size_t)src * H_;
    float* o = out + (size_t)rowid * H_;
    int c = threadIdx.x * 4;
    *(float4*)(o + c) = *(const float4*)(s + c);
}

// ---------------------------------------------------------------------------
extern "C" void kernel_launch(void* const* d_in, const int* in_sizes, int n_in,
                              void* d_out, int out_size, void* d_ws, size_t ws_size,
                              hipStream_t stream) {
    const float* x    = (const float*)d_in[0];
    const float* Wi0f = (const float*)d_in[1];
    const float* Wh0f = (const float*)d_in[2];
    const float* bi0  = (const float*)d_in[3];
    const float* bh0  = (const float*)d_in[4];
    const float* Wi1f = (const float*)d_in[5];
    const float* Wh1f = (const float*)d_in[6];
    const float* bi1  = (const float*)d_in[7];
    const float* bh1  = (const float*)d_in[8];
    const int*  bs       = (const int*)d_in[9];
    const int*  unsorted = (const int*)d_in[10];
    float* out = (float*)d_out;

    char* ws = (char*)d_ws;
    size_t off = 0;
    auto alloc = [&](size_t bytes) -> char* {
        char* p = ws + off;
        off += (bytes + 255) & ~(size_t)255;
        return p;
    };
    unsigned int* cnt = (unsigned int*)alloc(256);
    _Float16* x16 = (_Float16*)alloc((size_t)T_ * B_ * E_ * 2);
    _Float16* Wi0 = (_Float16*)alloc((size_t)3 * H_ * E_ * 2);
    _Float16* Wh0 = (_Float16*)alloc((size_t)3 * H_ * H_ * 2);
    _Float16* Wi1 = (_Float16*)alloc((size_t)3 * H_ * H_ * 2);
    _Float16* Wh1 = (_Float16*)alloc((size_t)3 * H_ * H_ * 2);
    float*    bias = (float*)alloc(2 * 4 * H_ * 4);
    char* zbase = ws + off;
    float*    h0f = (float*)alloc((size_t)BH * 4);
    float*    h1f = (float*)alloc((size_t)BH * 4);
    _Float16* h0h = (_Float16*)alloc((size_t)2 * BH * 2);
    _Float16* h1h = (_Float16*)alloc((size_t)2 * BH * 2);
    _Float16* hn0 = (_Float16*)alloc((size_t)2 * BH * 2);
    size_t zbytes = (size_t)((ws + off) - zbase);

    hipMemsetAsync(cnt, 0, 256, stream);
    hipMemsetAsync(zbase, 0, zbytes, stream);

    cvt_f32_f16<<<(T_ * B_ * E_) / 2048, 256, 0, stream>>>(x, x16, T_ * B_ * E_);
    cvt_f32_f16<<<(3 * H_ * E_) / 2048, 256, 0, stream>>>(Wi0f, Wi0, 3 * H_ * E_);
    cvt_f32_f16<<<(3 * H_ * H_) / 2048, 256, 0, stream>>>(Wh0f, Wh0, 3 * H_ * H_);
    cvt_f32_f16<<<(3 * H_ * H_) / 2048, 256, 0, stream>>>(Wi1f, Wi1, 3 * H_ * H_);
    cvt_f32_f16<<<(3 * H_ * H_) / 2048, 256, 0, stream>>>(Wh1f, Wh1, 3 * H_ * H_);
    prep_bias<<<8, 256, 0, stream>>>(bi0, bh0, bi1, bh1, bias);

    gru_persist<<<256, 256, 0, stream>>>(bs, x16, Wi0, Wh0, Wi1, Wh1, bias,
                                         h0f, h1f, h0h, h1h, hn0, cnt);

    gather_out<<<256, 256, 0, stream>>>(h0f, h1f, unsorted, out);
}

// Round 3
// 8102.868 us; speedup vs baseline: 1.6118x; 1.6118x over previous
//
#include <hip/hip_runtime.h>
#include <cstdint>
#include <cstddef>

#define T_ 256
#define B_ 128
#define E_ 512
#define H_ 1024
#define BH (B_*H_)

typedef _Float16 v8h __attribute__((ext_vector_type(8)));
typedef float    v4f __attribute__((ext_vector_type(4)));

__device__ __forceinline__ float sigmoidf_(float x){ return 1.0f/(1.0f+__expf(-x)); }
__device__ __forceinline__ float tanhf_(float x){ return 1.0f - 2.0f/(__expf(2.0f*x)+1.0f); }

// ---------------------------------------------------------------------------
// Device barrier, cheap version. Round-2 bug: ACQUIRE polls emit buffer_inv
// (full L2 invalidate) EVERY poll -> L2 thrash storm. Fix: relaxed polls,
// exactly one release (wbL2) before arrive and one acquire (invL2) after.
// __syncthreads drains all waves' vmcnt first (compiler-guaranteed).
// ---------------------------------------------------------------------------
__device__ __forceinline__ void grid_barrier(unsigned int* cnt, unsigned int target) {
    __syncthreads();
    if (threadIdx.x == 0) {
        __builtin_amdgcn_fence(__ATOMIC_RELEASE, "agent");   // one buffer_wbl2
        __hip_atomic_fetch_add(cnt, 1u, __ATOMIC_RELAXED, __HIP_MEMORY_SCOPE_AGENT);
        while (__hip_atomic_load(cnt, __ATOMIC_RELAXED, __HIP_MEMORY_SCOPE_AGENT) < target)
            __builtin_amdgcn_s_sleep(2);
        __builtin_amdgcn_fence(__ATOMIC_ACQUIRE, "agent");   // one buffer_inv
    }
    __syncthreads();
}

// ---------------------------------------------------------------------------
// One compile-time K-segment: NK ksteps of K=32. Loads ALL fragments first
// (NK*(4A+3B) dwordx4 loads in flight -> one latency exposure per segment),
// then the MFMAs. 16x16x32 f16, layouts verified in rounds 1-2.
// ---------------------------------------------------------------------------
template<int NK>
__device__ __forceinline__ void gemm_seg(
    v4f (&aR)[4], v4f (&aZ)[4], v4f (&aN)[4],
    const _Float16* __restrict__ A, int ap,
    const _Float16* __restrict__ Bw, int bp,
    int rtile, int ctile, int ks0, int lane)
{
    const int row = lane & 15, hi = lane >> 4;
    const _Float16* abase = A  + (size_t)(rtile + row) * ap + ks0 * 32 + hi * 8;
    const _Float16* bbase = Bw + (size_t)(ctile + row) * bp + ks0 * 32 + hi * 8;
    v8h afr[NK][4], bfr[NK][3];
#pragma unroll
    for (int k = 0; k < NK; ++k) {
#pragma unroll
        for (int m = 0; m < 4; ++m)
            afr[k][m] = *(const v8h*)(abase + (size_t)(m * 16) * ap + k * 32);
#pragma unroll
        for (int g = 0; g < 3; ++g)
            bfr[k][g] = *(const v8h*)(bbase + (size_t)(g * H_) * bp + k * 32);
    }
#pragma unroll
    for (int k = 0; k < NK; ++k) {
#pragma unroll
        for (int m = 0; m < 4; ++m) {
            aR[m] = __builtin_amdgcn_mfma_f32_16x16x32_f16(afr[k][m], bfr[k][0], aR[m], 0,0,0);
            aZ[m] = __builtin_amdgcn_mfma_f32_16x16x32_f16(afr[k][m], bfr[k][1], aZ[m], 0,0,0);
            aN[m] = __builtin_amdgcn_mfma_f32_16x16x32_f16(afr[k][m], bfr[k][2], aN[m], 0,0,0);
        }
    }
}

// ---------------------------------------------------------------------------
// Persistent fused 2-layer packed-seq GRU. 256 WGs x 256 thr, 1 WG/CU.
// WGs 0..127: layer0 @ t=k; 128..255: layer1 @ t=k-1. One barrier per step.
// WG tile 64 rows x 16 h-cols; 4 waves K-split; LDS reduce + fused epilogue.
// __launch_bounds__(256,1): 512-VGPR ceiling for deep load pipelining
// (round-2 had 96 VGPRs -> zero pipelining -> latency-bound).
// ---------------------------------------------------------------------------
__global__ __launch_bounds__(256, 1) void gru_persist(
    const int* __restrict__ bs, const _Float16* __restrict__ x16,
    const _Float16* __restrict__ Wi0, const _Float16* __restrict__ Wh0,
    const _Float16* __restrict__ Wi1, const _Float16* __restrict__ Wh1,
    const float* __restrict__ bias,
    float* __restrict__ h0f, float* __restrict__ h1f,
    _Float16* __restrict__ h0h, _Float16* __restrict__ h1h,
    _Float16* __restrict__ hn0,
    unsigned int* __restrict__ barrier_cnt)
{
    __shared__ float red[4][4][4][256];   // [wave][gate r,z,ni,nh][m-frag][16x16]
    __shared__ int bs_l[T_];

    const int b = blockIdx.x;
    const int phase = b >> 7;
    const int bl = b & 127;
    // weight-slice partners (mt 0/1) 8 apart -> same XCD L2
    const int mt  = (bl >> 3) & 1;
    const int jt  = ((bl >> 4) << 3) | (bl & 7);   // [0,64)
    const int rtile = mt * 64;
    const int ctile = jt * 16;

    const int tid = threadIdx.x, lane = tid & 63, w = tid >> 6;

    bs_l[tid] = bs[tid];          // T_ == 256 == blockDim.x

    // step-invariant epilogue constants (survive in regs across all steps)
    const float* bb = bias + phase * 4 * H_;
    const int col = ctile + (lane & 15);
    const float br_ = bb[col], bz_ = bb[H_ + col];
    const float bi_ = bb[2 * H_ + col], bh_ = bb[3 * H_ + col];
    float* hf = phase ? h1f : h0f;
    __syncthreads();

    for (int k = 0; k <= T_; ++k) {
        const int t = phase ? (k - 1) : k;
        const bool run = phase ? (k > 0) : (k < T_);
        if (run) {
            const int bs_t = bs_l[t];
            if (rtile < bs_t) {
                const int pr = t & 1, pw = 1 - pr;
                // hprev prefetch (epilogue-only use; issue before the GEMM)
                float hpv[4];
#pragma unroll
                for (int reg = 0; reg < 4; ++reg) {
                    const int row = rtile + 16 * w + (lane >> 4) * 4 + reg;
                    hpv[reg] = hf[(size_t)row * H_ + col];
                }
                v4f accR[4], accZ[4], accNi[4], accNh[4];
#pragma unroll
                for (int m = 0; m < 4; ++m) {
                    accR[m] = (v4f){0.f,0.f,0.f,0.f}; accZ[m]  = (v4f){0.f,0.f,0.f,0.f};
                    accNi[m] = (v4f){0.f,0.f,0.f,0.f}; accNh[m] = (v4f){0.f,0.f,0.f,0.f};
                }
                if (phase == 0) {
                    // x-seg: 16 ksteps -> wave w: [4w,4w+4); h-seg: 32 -> [8w,8w+8)
                    gemm_seg<4>(accR, accZ, accNi, x16 + (size_t)t * B_ * E_, E_,
                                Wi0, E_, rtile, ctile, 4 * w, lane);
                    gemm_seg<8>(accR, accZ, accNh, h0h + (size_t)pr * BH, H_,
                                Wh0, H_, rtile, ctile, 8 * w, lane);
                } else {
                    gemm_seg<8>(accR, accZ, accNi, hn0 + (size_t)pr * BH, H_,
                                Wi1, H_, rtile, ctile, 8 * w, lane);
                    gemm_seg<8>(accR, accZ, accNh, h1h + (size_t)pr * BH, H_,
                                Wh1, H_, rtile, ctile, 8 * w, lane);
                }
                // cross-wave K-reduction via LDS
#pragma unroll
                for (int m = 0; m < 4; ++m) {
                    *(v4f*)&red[w][0][m][lane * 4] = accR[m];
                    *(v4f*)&red[w][1][m][lane * 4] = accZ[m];
                    *(v4f*)&red[w][2][m][lane * 4] = accNi[m];
                    *(v4f*)&red[w][3][m][lane * 4] = accNh[m];
                }
                __syncthreads();
                v4f r4 = accR[w], z4 = accZ[w], n4i = accNi[w], n4h = accNh[w];
#pragma unroll
                for (int w2 = 0; w2 < 4; ++w2) {
                    if (w2 == w) continue;
                    r4  += *(const v4f*)&red[w2][0][w][lane * 4];
                    z4  += *(const v4f*)&red[w2][1][w][lane * 4];
                    n4i += *(const v4f*)&red[w2][2][w][lane * 4];
                    n4h += *(const v4f*)&red[w2][3][w][lane * 4];
                }
                _Float16* hh_w = (phase ? h1h : h0h) + (size_t)pw * BH;
                _Float16* hn0w = hn0 + (size_t)pr * BH;
#pragma unroll
                for (int reg = 0; reg < 4; ++reg) {
                    const int row = rtile + 16 * w + (lane >> 4) * 4 + reg;
                    const size_t off = (size_t)row * H_ + col;
                    const float hprev = hpv[reg];
                    const float rr = sigmoidf_(r4[reg] + br_);
                    const float zz = sigmoidf_(z4[reg] + bz_);
                    const float nn = tanhf_(n4i[reg] + bi_ + rr * (n4h[reg] + bh_));
                    const float hnew = (1.0f - zz) * nn + zz * hprev;
                    const bool act = row < bs_t;
                    if (phase == 0) hn0w[off] = (_Float16)hnew;  // layer1 input (unmasked)
                    hh_w[off] = (_Float16)(act ? hnew : hprev);
                    if (act) hf[off] = hnew;
                }
            }
            // rows/tiles with rtile >= bs_t: bs is non-increasing, so once a
            // tile is inactive it is never read again (its readers are the
            // same-rtile WGs, inactive together). No copy-forward needed.
        }
        grid_barrier(barrier_cnt, 256u * (unsigned)(k + 1));
    }
}

// ---------------------------------------------------------------------------
__global__ void cvt_f32_f16(const float* __restrict__ s, _Float16* __restrict__ d, int n) {
    int i = (blockIdx.x * 256 + threadIdx.x) * 8;
    if (i >= n) return;
    float4 v0 = *(const float4*)(s + i);
    float4 v1 = *(const float4*)(s + i + 4);
    v8h o = { (_Float16)v0.x, (_Float16)v0.y, (_Float16)v0.z, (_Float16)v0.w,
              (_Float16)v1.x, (_Float16)v1.y, (_Float16)v1.z, (_Float16)v1.w };
    *(v8h*)(d + i) = o;
}

__global__ void prep_bias(const float* __restrict__ bi0, const float* __restrict__ bh0,
                          const float* __restrict__ bi1, const float* __restrict__ bh1,
                          float* __restrict__ bias) {
    int tid = blockIdx.x * 256 + threadIdx.x;   // 2048 threads
    int l = tid >> 10, j = tid & 1023;
    const float* bi = l ? bi1 : bi0;
    const float* bh = l ? bh1 : bh0;
    float* o = bias + l * 4 * H_;
    o[j]          = bi[j] + bh[j];
    o[H_ + j]     = bi[H_ + j] + bh[H_ + j];
    o[2 * H_ + j] = bi[2 * H_ + j];
    o[3 * H_ + j] = bh[2 * H_ + j];
}

__global__ void gather_out(const float* __restrict__ h0f, const float* __restrict__ h1f,
                           const int* __restrict__ unsorted, float* __restrict__ out) {
    int rowid = blockIdx.x;          // 256 = L*B
    int l = rowid >> 7, b = rowid & 127;
    int src = unsorted[b];
    const float* s = (l ? h1f : h0f) + (size_t)src * H_;
    float* o = out + (size_t)rowid * H_;
    int c = threadIdx.x * 4;
    *(float4*)(o + c) = *(const float4*)(s + c);
}

// ---------------------------------------------------------------------------
extern "C" void kernel_launch(void* const* d_in, const int* in_sizes, int n_in,
                              void* d_out, int out_size, void* d_ws, size_t ws_size,
                              hipStream_t stream) {
    const float* x    = (const float*)d_in[0];
    const float* Wi0f = (const float*)d_in[1];
    const float* Wh0f = (const float*)d_in[2];
    const float* bi0  = (const float*)d_in[3];
    const float* bh0  = (const float*)d_in[4];
    const float* Wi1f = (const float*)d_in[5];
    const float* Wh1f = (const float*)d_in[6];
    const float* bi1  = (const float*)d_in[7];
    const float* bh1  = (const float*)d_in[8];
    const int*  bs       = (const int*)d_in[9];
    const int*  unsorted = (const int*)d_in[10];
    float* out = (float*)d_out;

    char* ws = (char*)d_ws;
    size_t off = 0;
    auto alloc = [&](size_t bytes) -> char* {
        char* p = ws + off;
        off += (bytes + 255) & ~(size_t)255;
        return p;
    };
    unsigned int* cnt = (unsigned int*)alloc(256);
    _Float16* x16 = (_Float16*)alloc((size_t)T_ * B_ * E_ * 2);
    _Float16* Wi0 = (_Float16*)alloc((size_t)3 * H_ * E_ * 2);
    _Float16* Wh0 = (_Float16*)alloc((size_t)3 * H_ * H_ * 2);
    _Float16* Wi1 = (_Float16*)alloc((size_t)3 * H_ * H_ * 2);
    _Float16* Wh1 = (_Float16*)alloc((size_t)3 * H_ * H_ * 2);
    float*    bias = (float*)alloc(2 * 4 * H_ * 4);
    char* zbase = ws + off;
    float*    h0f = (float*)alloc((size_t)BH * 4);
    float*    h1f = (float*)alloc((size_t)BH * 4);
    _Float16* h0h = (_Float16*)alloc((size_t)2 * BH * 2);
    _Float16* h1h = (_Float16*)alloc((size_t)2 * BH * 2);
    _Float16* hn0 = (_Float16*)alloc((size_t)2 * BH * 2);
    size_t zbytes = (size_t)((ws + off) - zbase);

    hipMemsetAsync(cnt, 0, 256, stream);
    hipMemsetAsync(zbase, 0, zbytes, stream);

    cvt_f32_f16<<<(T_ * B_ * E_) / 2048, 256, 0, stream>>>(x, x16, T_ * B_ * E_);
    cvt_f32_f16<<<(3 * H_ * E_) / 2048, 256, 0, stream>>>(Wi0f, Wi0, 3 * H_ * E_);
    cvt_f32_f16<<<(3 * H_ * H_) / 2048, 256, 0, stream>>>(Wh0f, Wh0, 3 * H_ * H_);
    cvt_f32_f16<<<(3 * H_ * H_) / 2048, 256, 0, stream>>>(Wi1f, Wi1, 3 * H_ * H_);
    cvt_f32_f16<<<(3 * H_ * H_) / 2048, 256, 0, stream>>>(Wh1f, Wh1, 3 * H_ * H_);
    prep_bias<<<8, 256, 0, stream>>>(bi0, bh0, bi1, bh1, bias);

    gru_persist<<<256, 256, 0, stream>>>(bs, x16, Wi0, Wh0, Wi1, Wh1, bias,
                                         h0f, h1f, h0h, h1h, hn0, cnt);

    gather_out<<<256, 256, 0, stream>>>(h0f, h1f, unsorted, out);
}